// Round 9
// baseline (1839.502 us; speedup 1.0000x reference)
//
#include <hip/hip_runtime.h>
#include <stdint.h>

// Problem constants (fixed instance from setup_inputs)
#define B_   2
#define T_   64
#define S_   1024
#define C_   512
#define H_   8
#define N_   (T_ * S_)      // 65536
#define M_   (B_ * N_)      // 131072
#define WIN_ 5

typedef unsigned short u16;
typedef __bf16 bf16;
typedef __bf16 bf16x8 __attribute__((ext_vector_type(8)));
typedef float  f32x4  __attribute__((ext_vector_type(4)));
typedef u16    u16x8  __attribute__((ext_vector_type(8)));

static __device__ __forceinline__ u16 f2bf(float f) {
    return __builtin_bit_cast(u16, (bf16)f);   // RNE
}
static __device__ __forceinline__ float bf2f(u16 u) {
    return __builtin_bit_cast(float, (uint32_t)u << 16);
}
// async global->LDS, 16B per lane; LDS dest is wave-uniform base + lane*16
static __device__ __forceinline__ void gload16(const void* g, void* l) {
    __builtin_amdgcn_global_load_lds(
        (const __attribute__((address_space(1))) void*)g,
        (__attribute__((address_space(3))) void*)l, 16, 0, 0);
}
// row permutation: logical (b,t,s) flat row -> physical (b,s,t) flat row
static __device__ __forceinline__ long permute_row(long grow) {
    int b = (int)(grow >> 16);
    int t = (int)(grow >> 10) & 63;
    int s = (int)grow & 1023;
    return ((long)((b << 10) | s)) * 64 + t;
}

// Pre-swizzle layout (every bf16 [row][512] operand, row = PHYSICAL row):
// logical (chunk c in [0,16) of 32 elems, granule g in [0,4), elem j) stored
// at r*512 + (c ^ ((r>>3)&1))*32 + ((g ^ ((r>>1)&3))<<3) + j, keys from the
// row index mod 256 (= the GEMM tile-local LDS row). 0 bank conflicts measured.

// ---------------------------------------------------------------------------
// Weight prep: W [512][NCOL] fp32 -> WT [NCOL][512] bf16, pre-swizzled.
// ---------------------------------------------------------------------------
__global__ __launch_bounds__(256) void prep_w(const float* __restrict__ W,
                                              u16* __restrict__ WT, int NCOL) {
    int id = blockIdx.x * 256 + threadIdx.x;
    int n  = id % NCOL;
    int gi = id / NCOL;
    int chunk = gi >> 2;
    int g     = gi & 3;
    int k0 = chunk * 32 + g * 8;
    int cs = chunk ^ ((n >> 3) & 1);
    int gs = g ^ ((n >> 1) & 3);
    u16x8 w;
    #pragma unroll
    for (int j = 0; j < 8; ++j) w[j] = f2bf(W[(size_t)(k0 + j) * NCOL + n]);
    *(u16x8*)&WT[(size_t)n * 512 + cs * 32 + gs * 8] = w;
}

// ---------------------------------------------------------------------------
// x prep: x [M][512] fp32 (rows (b,t,s)) -> xb bf16 rows PERMUTED to (b,s,t),
// pre-swizzled with keys from the permuted row index.
// ---------------------------------------------------------------------------
__global__ __launch_bounds__(256) void prep_x(const float* __restrict__ x,
                                              u16* __restrict__ xb) {
    const size_t total = (size_t)M_ * 64;   // 16B granules
    for (size_t id = (size_t)blockIdx.x * 256 + threadIdx.x; id < total;
         id += (size_t)gridDim.x * 256) {
        long r_in = (long)(id >> 6);
        int  gi   = (int)(id & 63);
        int chunk = gi >> 2;
        int g     = gi & 3;
        long rid  = permute_row(r_in);
        int cb  = (int)(rid >> 3) & 1;
        int key = (int)(rid >> 1) & 3;
        const float* src = x + r_in * 512 + chunk * 32 + g * 8;
        f32x4 v0 = *(const f32x4*)(src);
        f32x4 v1 = *(const f32x4*)(src + 4);
        u16x8 w;
        #pragma unroll
        for (int j = 0; j < 4; ++j) { w[j] = f2bf(v0[j]); w[4 + j] = f2bf(v1[j]); }
        *(u16x8*)&xb[(size_t)rid * 512 + (chunk ^ cb) * 32 + ((g ^ key) << 3)] = w;
    }
}

#define LDF(off) __builtin_bit_cast(bf16x8, *(const u16x8*)&lds[(off)])
#define MFMA16(d, a, b) d = __builtin_amdgcn_mfma_f32_16x16x32_bf16(a, b, d, 0, 0, 0)

// ---------------------------------------------------------------------------
// 256x256 8-phase pipelined GEMM (round-7 structure + balanced {8,8,4,4}
// phase reads). A rows: physical = A_PERM ? permute_row(logical) : logical;
// B(transposed) [NCOL][512]; both pre-swizzled bf16.
// 512 thr = 8 waves (2 wm x 4 wn), BK=64, 2 K-tile dbuf (128 KiB LDS).
// Per K-tile t, 4 phases {reads | stage half-tile | barrier | lgkmcnt(0) |
// 16 MFMA (setprio) | barrier}:
//   ph0: af0_lo(4)+bf0(4); stage A(t+1,0); MFMA mf0-3 kk0
//   ph1: af0_hi(4)+bf1(4); stage A(t+1,1); MFMA mf4-7 kk0
//   ph2: af1_lo(4);        stage B(t+2,0); MFMA mf0-3 kk1
//   ph3: af1_hi(4);        stage B(t+2,1); MFMA mf4-7 kk1; vmcnt(4)
// WAR: A(t+1)->other dbuf (its reads drained by t-1 ph3 lgkm+barrier);
// B(t+2)->this dbuf's B (all B reads done by ph1 lgkm+barrier).
// vmcnt(4) at tile end keeps B(t+2) in flight; vmcnt(0) only at t=6.
// ---------------------------------------------------------------------------
template<int NCOL, bool OUT_BF16, bool A_PERM>
__global__ __launch_bounds__(512, 2) void gemm8_k(const u16* __restrict__ Ap,
                                                  const u16* __restrict__ Bp,
                                                  void* __restrict__ Dp, int gx) {
    __shared__ u16 lds[65536];   // dbuf0{A,B} | dbuf1{A,B}, 16384 u16 each

    const int tid  = threadIdx.x;
    const int lane = tid & 63;
    const int wid  = tid >> 6;    // 0..7
    const int wm   = wid >> 2;    // 0..1
    const int wn   = wid & 3;     // 0..3
    const int fr   = lane & 15;
    const int g0   = lane >> 4;

    // XCD-aware bijective swizzle (grid % 8 == 0)
    const int nwg = gridDim.x;
    const int q8  = nwg >> 3;
    const int bid = blockIdx.x;
    const int wg  = (bid & 7) * q8 + (bid >> 3);
    const int bx  = wg % gx;
    const int by  = wg / gx;
    const long row0 = (long)by * 256;
    const int  col0 = bx * 256;

    // per-frag LDS offsets (u16, rel. to A/B region base), kk=0; kk=1 = ^32
    int aoffs[8], boffs[4];
    #pragma unroll
    for (int mf = 0; mf < 8; ++mf) {
        int lr = wm * 128 + mf * 16 + fr;
        aoffs[mf] = lr * 64 + (((lr >> 3) & 1) << 5) + (((g0 ^ (lr >> 1)) & 3) << 3);
    }
    #pragma unroll
    for (int nf = 0; nf < 4; ++nf) {
        int lc = wn * 64 + nf * 16 + fr;
        boffs[nf] = lc * 64 + (((lc >> 3) & 1) << 5) + (((g0 ^ (lc >> 1)) & 3) << 3);
    }

    const int srow = lane >> 3;        // staging: row within 8-row wave slab
    const int scol = (lane & 7) * 8;   // u16 offset within 128B row window

    // precompute A staging physical row bases (4 rows per thread)
    long arow_phys[4];
    #pragma unroll
    for (int half = 0; half < 2; ++half)
        #pragma unroll
        for (int i = 0; i < 2; ++i) {
            int r = half * 128 + i * 64 + wid * 8 + srow;
            long grow = row0 + r;
            arow_phys[half * 2 + i] = A_PERM ? permute_row(grow) : grow;
        }

    // stage one half-tile (128 rows x 64 k): 2 gload16 per thread
    auto stageA = [&](int tt, int half) {
        const int ab = (tt & 1) * 32768;
        #pragma unroll
        for (int i = 0; i < 2; ++i) {
            int r = half * 128 + i * 64 + wid * 8 + srow;
            const u16* g = Ap + arow_phys[half * 2 + i] * 512 + tt * 64 + scol;
            gload16(g, (void*)&lds[ab + r * 64]);
        }
    };
    auto stageB = [&](int tt, int half) {
        const int ab = (tt & 1) * 32768;
        #pragma unroll
        for (int i = 0; i < 2; ++i) {
            int r = half * 128 + i * 64 + wid * 8 + srow;
            const u16* g = Bp + (size_t)(col0 + r) * 512 + tt * 64 + scol;
            gload16(g, (void*)&lds[ab + 16384 + r * 64]);
        }
    };

    f32x4 acc[8][4] = {};

    // ---- prologue: tile0 full + tile1 B (12 loads); keep B(t1) in flight ----
    stageA(0, 0); stageA(0, 1); stageB(0, 0); stageB(0, 1);
    stageB(1, 0); stageB(1, 1);
    asm volatile("s_waitcnt vmcnt(4)" ::: "memory");
    __builtin_amdgcn_sched_barrier(0);
    __builtin_amdgcn_s_barrier();

    #pragma unroll
    for (int t = 0; t < 8; ++t) {
        const int ab = (t & 1) * 32768;
        bf16x8 af0[8], af1[8], bf0[4], bf1[4];
        // ================= phase 0 =================
        #pragma unroll
        for (int mf = 0; mf < 4; ++mf) af0[mf] = LDF(ab + aoffs[mf]);
        #pragma unroll
        for (int nf = 0; nf < 4; ++nf) bf0[nf] = LDF(ab + 16384 + boffs[nf]);
        if (t <= 6) stageA(t + 1, 0);
        __builtin_amdgcn_s_barrier();
        asm volatile("s_waitcnt lgkmcnt(0)" ::: "memory");
        __builtin_amdgcn_sched_barrier(0);
        __builtin_amdgcn_s_setprio(1);
        #pragma unroll
        for (int mf = 0; mf < 4; ++mf) {
            MFMA16(acc[mf][0], af0[mf], bf0[0]);
            MFMA16(acc[mf][1], af0[mf], bf0[1]);
            MFMA16(acc[mf][2], af0[mf], bf0[2]);
            MFMA16(acc[mf][3], af0[mf], bf0[3]);
        }
        __builtin_amdgcn_s_setprio(0);
        __builtin_amdgcn_s_barrier();
        // ================= phase 1 =================
        #pragma unroll
        for (int mf = 4; mf < 8; ++mf) af0[mf] = LDF(ab + aoffs[mf]);
        #pragma unroll
        for (int nf = 0; nf < 4; ++nf) bf1[nf] = LDF(ab + 16384 + (boffs[nf] ^ 32));
        if (t <= 6) stageA(t + 1, 1);
        __builtin_amdgcn_s_barrier();
        asm volatile("s_waitcnt lgkmcnt(0)" ::: "memory");
        __builtin_amdgcn_sched_barrier(0);
        __builtin_amdgcn_s_setprio(1);
        #pragma unroll
        for (int mf = 4; mf < 8; ++mf) {
            MFMA16(acc[mf][0], af0[mf], bf0[0]);
            MFMA16(acc[mf][1], af0[mf], bf0[1]);
            MFMA16(acc[mf][2], af0[mf], bf0[2]);
            MFMA16(acc[mf][3], af0[mf], bf0[3]);
        }
        __builtin_amdgcn_s_setprio(0);
        __builtin_amdgcn_s_barrier();
        // ================= phase 2 =================
        #pragma unroll
        for (int mf = 0; mf < 4; ++mf) af1[mf] = LDF(ab + (aoffs[mf] ^ 32));
        if (t <= 5) stageB(t + 2, 0);
        __builtin_amdgcn_s_barrier();
        asm volatile("s_waitcnt lgkmcnt(0)" ::: "memory");
        __builtin_amdgcn_sched_barrier(0);
        __builtin_amdgcn_s_setprio(1);
        #pragma unroll
        for (int mf = 0; mf < 4; ++mf) {
            MFMA16(acc[mf][0], af1[mf], bf1[0]);
            MFMA16(acc[mf][1], af1[mf], bf1[1]);
            MFMA16(acc[mf][2], af1[mf], bf1[2]);
            MFMA16(acc[mf][3], af1[mf], bf1[3]);
        }
        __builtin_amdgcn_s_setprio(0);
        __builtin_amdgcn_s_barrier();
        // ================= phase 3 =================
        #pragma unroll
        for (int mf = 4; mf < 8; ++mf) af1[mf] = LDF(ab + (aoffs[mf] ^ 32));
        if (t <= 5) stageB(t + 2, 1);
        __builtin_amdgcn_s_barrier();
        asm volatile("s_waitcnt lgkmcnt(0)" ::: "memory");
        __builtin_amdgcn_sched_barrier(0);
        __builtin_amdgcn_s_setprio(1);
        #pragma unroll
        for (int mf = 4; mf < 8; ++mf) {
            MFMA16(acc[mf][0], af1[mf], bf1[0]);
            MFMA16(acc[mf][1], af1[mf], bf1[1]);
            MFMA16(acc[mf][2], af1[mf], bf1[2]);
            MFMA16(acc[mf][3], af1[mf], bf1[3]);
        }
        __builtin_amdgcn_s_setprio(0);
        if (t <= 5) {
            asm volatile("s_waitcnt vmcnt(4)" ::: "memory");   // t+1 landed, B(t+2) in flight
        } else if (t == 6) {
            asm volatile("s_waitcnt vmcnt(0)" ::: "memory");   // drain before last tile
        }
        __builtin_amdgcn_sched_barrier(0);
        __builtin_amdgcn_s_barrier();
    }

    // ---- epilogue: C row = (lane>>4)*4 + r, col = lane&15 (logical rows) ----
    #pragma unroll
    for (int mf = 0; mf < 8; ++mf) {
        #pragma unroll
        for (int nf = 0; nf < 4; ++nf) {
            #pragma unroll
            for (int r = 0; r < 4; ++r) {
                long grow = row0 + wm * 128 + mf * 16 + (lane >> 4) * 4 + r;
                int  gcol = col0 + wn * 64 + nf * 16 + fr;
                float v = acc[mf][nf][r];
                if constexpr (OUT_BF16) ((u16*)Dp)[grow * NCOL + gcol] = f2bf(v);
                else                    ((float*)Dp)[grow * NCOL + gcol] = v;
            }
        }
    }
}

// ---------------------------------------------------------------------------
// Banded temporal attention, DIRECT-GLOBAL (no LDS, no barriers).
// One wave per (b, h, s), grid h-fastest. qkv rows (b,s,t)-ordered, so one
// unit's working set is a strided subset of a contiguous 192 KB slab; each
// wave's Q/K/V head-slices (24 KB, heavily lane-overlapped) are L1-resident.
// Occupancy is VGPR-bound (no LDS cap), ~2.5x the staged version.
// Output row rid stored PRE-SWIZZLED with s-based keys for gemm3.
// ---------------------------------------------------------------------------
__global__ __launch_bounds__(64) void attn_k(const u16* __restrict__ qkv,
                                             u16* __restrict__ attn) {
    const int bid = blockIdx.x;
    const int h = bid & (H_ - 1);
    const int s = (bid >> 3) & (S_ - 1);
    const int b = bid >> 13;
    const int t = threadIdx.x;

    const size_t base = ((size_t)((b << 10) | s) * 64) * 1536 + h * 64;

    // Q row (fp32 in regs)
    float qf[64];
    {
        const u16* qp = qkv + base + (size_t)t * 1536;
        #pragma unroll
        for (int c = 0; c < 8; ++c) {
            u16x8 v = *(const u16x8*)(qp + c * 8);
            #pragma unroll
            for (int j = 0; j < 8; ++j) qf[c * 8 + j] = bf2f(v[j]);
        }
    }

    // band scores (K rows read direct; lanes overlap 10/11 rows -> L1 hits)
    float p[11];
    float m = -1e30f;
    #pragma unroll
    for (int i = 0; i < 11; ++i) {
        int u = t - WIN_ + i;
        if (u >= 0 && u < 64) {
            const u16* kp = qkv + base + (size_t)u * 1536 + 512;
            float dot = 0.f;
            #pragma unroll
            for (int c = 0; c < 8; ++c) {
                u16x8 kv = *(const u16x8*)(kp + c * 8);
                #pragma unroll
                for (int j = 0; j < 8; ++j) dot += qf[c * 8 + j] * bf2f(kv[j]);
            }
            p[i] = dot * 0.125f;   // hd^-0.5
            m = fmaxf(m, p[i]);
        } else {
            p[i] = -1e30f;
        }
    }
    float sum = 0.f;
    #pragma unroll
    for (int i = 0; i < 11; ++i) {
        int u = t - WIN_ + i;
        float e = (u >= 0 && u < 64) ? __expf(p[i] - m) : 0.f;
        p[i] = e;
        sum += e;
    }
    const float inv = 1.f / sum;

    // PV (V rows read direct)
    float o[64];
    #pragma unroll
    for (int d = 0; d < 64; ++d) o[d] = 0.f;
    #pragma unroll
    for (int i = 0; i < 11; ++i) {
        int u = t - WIN_ + i;
        if (u >= 0 && u < 64) {
            const u16* vp = qkv + base + (size_t)u * 1536 + 1024;
            float pv = p[i] * inv;
            #pragma unroll
            for (int c = 0; c < 8; ++c) {
                u16x8 vv = *(const u16x8*)(vp + c * 8);
                #pragma unroll
                for (int j = 0; j < 8; ++j) o[c * 8 + j] += pv * bf2f(vv[j]);
            }
        }
    }
    // pre-swizzled store at physical row rid; keys from s (gemm3-local row)
    size_t rowbase = ((size_t)((b << 10) | s) * 64 + t) * (size_t)C_;
    const int cb  = (s >> 3) & 1;
    const int key = (s >> 1) & 3;
    #pragma unroll
    for (int c = 0; c < 8; ++c) {
        u16x8 w;
        #pragma unroll
        for (int j = 0; j < 8; ++j) w[j] = f2bf(o[c * 8 + j]);
        int off = (((2 * h + (c >> 2)) ^ cb) << 5) + (((c & 3) ^ key) << 3);
        *(u16x8*)&attn[rowbase + off] = w;
    }
}

// ---------------------------------------------------------------------------
extern "C" void kernel_launch(void* const* d_in, const int* in_sizes, int n_in,
                              void* d_out, int out_size, void* d_ws, size_t ws_size,
                              hipStream_t stream) {
    const float* x    = (const float*)d_in[0];   // (B, N, C) fp32
    const float* Wqkv = (const float*)d_in[1];   // (512, 1536) fp32
    const float* Wout = (const float*)d_in[2];   // (512, 512) fp32
    float* out = (float*)d_out;

    const size_t xc_elems  = (size_t)M_ * C_;      // 67.1M (x_bf16 / attn alias)
    const size_t qkv_elems = (size_t)M_ * 1536;    // 201.3M
    if (ws_size < (xc_elems + qkv_elems) * sizeof(u16)) return;  // 537 MiB

    u16* xb       = (u16*)d_ws;              // [0, 134MB): x_bf16 (b,s,t)-rows
    u16* qkv      = xb + xc_elems;           // [134MB, 537MB), (b,s,t)-rows
    u16* attn_buf = xb;                      // alias: written after xb is dead
    u16* WqkvT    = (u16*)d_out;             // scratch in d_out (dead until gemm3)
    u16* WoutT    = qkv;                     // alias: written after qkv is dead

    // 1) weight + activation prep (bf16, pre-swizzled; x rows permuted)
    prep_w<<<(1536 * 64) / 256, 256, 0, stream>>>(Wqkv, WqkvT, 1536);
    prep_x<<<8192, 256, 0, stream>>>(x, xb);

    // 2) qkv = x @ W_qkv  (256^2 8-phase, bf16 out, rows already permuted)
    gemm8_k<1536, true, false><<<3072, 512, 0, stream>>>(xb, WqkvT, (void*)qkv, 6);

    // 3) banded temporal attention (direct-global, no LDS)
    attn_k<<<B_ * H_ * S_, 64, 0, stream>>>(qkv, attn_buf);

    // 4) WoutT into the now-dead qkv region
    prep_w<<<(512 * 64) / 256, 256, 0, stream>>>(Wout, WoutT, 512);

    // 5) out = attn @ W_out  (256^2 8-phase, fp32 out coalesced; A un-permuted
    //    via per-lane gload addresses, attn_buf is L3-resident)
    gemm8_k<512, false, true><<<1024, 512, 0, stream>>>(attn_buf, WoutT, (void*)out, 2);
}

// Round 11
// 610.118 us; speedup vs baseline: 3.0150x; 3.0150x over previous
//
#include <hip/hip_runtime.h>
#include <stdint.h>

// Problem constants (fixed instance from setup_inputs)
#define B_   2
#define T_   64
#define S_   1024
#define C_   512
#define H_   8
#define N_   (T_ * S_)      // 65536
#define M_   (B_ * N_)      // 131072
#define WIN_ 5

typedef unsigned short u16;
typedef __bf16 bf16;
typedef __bf16 bf16x8 __attribute__((ext_vector_type(8)));
typedef float  f32x4  __attribute__((ext_vector_type(4)));
typedef u16    u16x8  __attribute__((ext_vector_type(8)));

static __device__ __forceinline__ u16 f2bf(float f) {
    return __builtin_bit_cast(u16, (bf16)f);   // RNE
}
static __device__ __forceinline__ float bf2f(u16 u) {
    return __builtin_bit_cast(float, (uint32_t)u << 16);
}
// async global->LDS, 16B per lane; LDS dest is wave-uniform base + lane*16
static __device__ __forceinline__ void gload16(const void* g, void* l) {
    __builtin_amdgcn_global_load_lds(
        (const __attribute__((address_space(1))) void*)g,
        (__attribute__((address_space(3))) void*)l, 16, 0, 0);
}
// row permutation: logical (b,t,s) flat row -> physical (b,s,t) flat row
static __device__ __forceinline__ long permute_row(long grow) {
    int b = (int)(grow >> 16);
    int t = (int)(grow >> 10) & 63;
    int s = (int)grow & 1023;
    return ((long)((b << 10) | s)) * 64 + t;
}

// Pre-swizzle layout (every bf16 [row][512] operand, row = PHYSICAL row):
// logical (chunk c in [0,16) of 32 elems, granule g in [0,4), elem j) stored
// at r*512 + (c ^ ((r>>3)&1))*32 + ((g ^ ((r>>1)&3))<<3) + j, keys from the
// row index mod 256 (= the GEMM tile-local LDS row). 0 bank conflicts measured.

// ---------------------------------------------------------------------------
// Weight prep: W [512][NCOL] fp32 -> WT [NCOL][512] bf16, pre-swizzled.
// ---------------------------------------------------------------------------
__global__ __launch_bounds__(256) void prep_w(const float* __restrict__ W,
                                              u16* __restrict__ WT, int NCOL) {
    int id = blockIdx.x * 256 + threadIdx.x;
    int n  = id % NCOL;
    int gi = id / NCOL;
    int chunk = gi >> 2;
    int g     = gi & 3;
    int k0 = chunk * 32 + g * 8;
    int cs = chunk ^ ((n >> 3) & 1);
    int gs = g ^ ((n >> 1) & 3);
    u16x8 w;
    #pragma unroll
    for (int j = 0; j < 8; ++j) w[j] = f2bf(W[(size_t)(k0 + j) * NCOL + n]);
    *(u16x8*)&WT[(size_t)n * 512 + cs * 32 + gs * 8] = w;
}

// ---------------------------------------------------------------------------
// x prep: x [M][512] fp32 (rows (b,t,s)) -> xb bf16 rows PERMUTED to (b,s,t),
// pre-swizzled with keys from the permuted row index.
// ---------------------------------------------------------------------------
__global__ __launch_bounds__(256) void prep_x(const float* __restrict__ x,
                                              u16* __restrict__ xb) {
    const size_t total = (size_t)M_ * 64;   // 16B granules
    for (size_t id = (size_t)blockIdx.x * 256 + threadIdx.x; id < total;
         id += (size_t)gridDim.x * 256) {
        long r_in = (long)(id >> 6);
        int  gi   = (int)(id & 63);
        int chunk = gi >> 2;
        int g     = gi & 3;
        long rid  = permute_row(r_in);
        int cb  = (int)(rid >> 3) & 1;
        int key = (int)(rid >> 1) & 3;
        const float* src = x + r_in * 512 + chunk * 32 + g * 8;
        f32x4 v0 = *(const f32x4*)(src);
        f32x4 v1 = *(const f32x4*)(src + 4);
        u16x8 w;
        #pragma unroll
        for (int j = 0; j < 4; ++j) { w[j] = f2bf(v0[j]); w[4 + j] = f2bf(v1[j]); }
        *(u16x8*)&xb[(size_t)rid * 512 + (chunk ^ cb) * 32 + ((g ^ key) << 3)] = w;
    }
}

#define LDF(off) __builtin_bit_cast(bf16x8, *(const u16x8*)&lds[(off)])
#define MFMA16(d, a, b) d = __builtin_amdgcn_mfma_f32_16x16x32_bf16(a, b, d, 0, 0, 0)

// ---------------------------------------------------------------------------
// 256x256 8-phase pipelined GEMM (round-7 structure + balanced {8,8,4,4}
// phase reads; validated r9). A rows: physical = A_PERM ? permute_row : id;
// B(transposed) [NCOL][512]; both pre-swizzled bf16.
// 512 thr = 8 waves (2 wm x 4 wn), BK=64, 2 K-tile dbuf (128 KiB LDS).
// ---------------------------------------------------------------------------
template<int NCOL, bool OUT_BF16, bool A_PERM>
__global__ __launch_bounds__(512, 2) void gemm8_k(const u16* __restrict__ Ap,
                                                  const u16* __restrict__ Bp,
                                                  void* __restrict__ Dp, int gx) {
    __shared__ u16 lds[65536];   // dbuf0{A,B} | dbuf1{A,B}, 16384 u16 each

    const int tid  = threadIdx.x;
    const int lane = tid & 63;
    const int wid  = tid >> 6;    // 0..7
    const int wm   = wid >> 2;    // 0..1
    const int wn   = wid & 3;     // 0..3
    const int fr   = lane & 15;
    const int g0   = lane >> 4;

    // XCD-aware bijective swizzle (grid % 8 == 0)
    const int nwg = gridDim.x;
    const int q8  = nwg >> 3;
    const int bid = blockIdx.x;
    const int wg  = (bid & 7) * q8 + (bid >> 3);
    const int bx  = wg % gx;
    const int by  = wg / gx;
    const long row0 = (long)by * 256;
    const int  col0 = bx * 256;

    // per-frag LDS offsets (u16, rel. to A/B region base), kk=0; kk=1 = ^32
    int aoffs[8], boffs[4];
    #pragma unroll
    for (int mf = 0; mf < 8; ++mf) {
        int lr = wm * 128 + mf * 16 + fr;
        aoffs[mf] = lr * 64 + (((lr >> 3) & 1) << 5) + (((g0 ^ (lr >> 1)) & 3) << 3);
    }
    #pragma unroll
    for (int nf = 0; nf < 4; ++nf) {
        int lc = wn * 64 + nf * 16 + fr;
        boffs[nf] = lc * 64 + (((lc >> 3) & 1) << 5) + (((g0 ^ (lc >> 1)) & 3) << 3);
    }

    const int srow = lane >> 3;        // staging: row within 8-row wave slab
    const int scol = (lane & 7) * 8;   // u16 offset within 128B row window

    // precompute A staging physical row bases (4 rows per thread)
    long arow_phys[4];
    #pragma unroll
    for (int half = 0; half < 2; ++half)
        #pragma unroll
        for (int i = 0; i < 2; ++i) {
            int r = half * 128 + i * 64 + wid * 8 + srow;
            long grow = row0 + r;
            arow_phys[half * 2 + i] = A_PERM ? permute_row(grow) : grow;
        }

    // stage one half-tile (128 rows x 64 k): 2 gload16 per thread
    auto stageA = [&](int tt, int half) {
        const int ab = (tt & 1) * 32768;
        #pragma unroll
        for (int i = 0; i < 2; ++i) {
            int r = half * 128 + i * 64 + wid * 8 + srow;
            const u16* g = Ap + arow_phys[half * 2 + i] * 512 + tt * 64 + scol;
            gload16(g, (void*)&lds[ab + r * 64]);
        }
    };
    auto stageB = [&](int tt, int half) {
        const int ab = (tt & 1) * 32768;
        #pragma unroll
        for (int i = 0; i < 2; ++i) {
            int r = half * 128 + i * 64 + wid * 8 + srow;
            const u16* g = Bp + (size_t)(col0 + r) * 512 + tt * 64 + scol;
            gload16(g, (void*)&lds[ab + 16384 + r * 64]);
        }
    };

    f32x4 acc[8][4] = {};

    // ---- prologue: tile0 full + tile1 B (12 loads); keep B(t1) in flight ----
    stageA(0, 0); stageA(0, 1); stageB(0, 0); stageB(0, 1);
    stageB(1, 0); stageB(1, 1);
    asm volatile("s_waitcnt vmcnt(4)" ::: "memory");
    __builtin_amdgcn_sched_barrier(0);
    __builtin_amdgcn_s_barrier();

    #pragma unroll
    for (int t = 0; t < 8; ++t) {
        const int ab = (t & 1) * 32768;
        bf16x8 af0[8], af1[8], bf0[4], bf1[4];
        // ================= phase 0 =================
        #pragma unroll
        for (int mf = 0; mf < 4; ++mf) af0[mf] = LDF(ab + aoffs[mf]);
        #pragma unroll
        for (int nf = 0; nf < 4; ++nf) bf0[nf] = LDF(ab + 16384 + boffs[nf]);
        if (t <= 6) stageA(t + 1, 0);
        __builtin_amdgcn_s_barrier();
        asm volatile("s_waitcnt lgkmcnt(0)" ::: "memory");
        __builtin_amdgcn_sched_barrier(0);
        __builtin_amdgcn_s_setprio(1);
        #pragma unroll
        for (int mf = 0; mf < 4; ++mf) {
            MFMA16(acc[mf][0], af0[mf], bf0[0]);
            MFMA16(acc[mf][1], af0[mf], bf0[1]);
            MFMA16(acc[mf][2], af0[mf], bf0[2]);
            MFMA16(acc[mf][3], af0[mf], bf0[3]);
        }
        __builtin_amdgcn_s_setprio(0);
        __builtin_amdgcn_s_barrier();
        // ================= phase 1 =================
        #pragma unroll
        for (int mf = 4; mf < 8; ++mf) af0[mf] = LDF(ab + aoffs[mf]);
        #pragma unroll
        for (int nf = 0; nf < 4; ++nf) bf1[nf] = LDF(ab + 16384 + (boffs[nf] ^ 32));
        if (t <= 6) stageA(t + 1, 1);
        __builtin_amdgcn_s_barrier();
        asm volatile("s_waitcnt lgkmcnt(0)" ::: "memory");
        __builtin_amdgcn_sched_barrier(0);
        __builtin_amdgcn_s_setprio(1);
        #pragma unroll
        for (int mf = 4; mf < 8; ++mf) {
            MFMA16(acc[mf][0], af0[mf], bf0[0]);
            MFMA16(acc[mf][1], af0[mf], bf0[1]);
            MFMA16(acc[mf][2], af0[mf], bf0[2]);
            MFMA16(acc[mf][3], af0[mf], bf0[3]);
        }
        __builtin_amdgcn_s_setprio(0);
        __builtin_amdgcn_s_barrier();
        // ================= phase 2 =================
        #pragma unroll
        for (int mf = 0; mf < 4; ++mf) af1[mf] = LDF(ab + (aoffs[mf] ^ 32));
        if (t <= 5) stageB(t + 2, 0);
        __builtin_amdgcn_s_barrier();
        asm volatile("s_waitcnt lgkmcnt(0)" ::: "memory");
        __builtin_amdgcn_sched_barrier(0);
        __builtin_amdgcn_s_setprio(1);
        #pragma unroll
        for (int mf = 0; mf < 4; ++mf) {
            MFMA16(acc[mf][0], af1[mf], bf1[0]);
            MFMA16(acc[mf][1], af1[mf], bf1[1]);
            MFMA16(acc[mf][2], af1[mf], bf1[2]);
            MFMA16(acc[mf][3], af1[mf], bf1[3]);
        }
        __builtin_amdgcn_s_setprio(0);
        __builtin_amdgcn_s_barrier();
        // ================= phase 3 =================
        #pragma unroll
        for (int mf = 4; mf < 8; ++mf) af1[mf] = LDF(ab + (aoffs[mf] ^ 32));
        if (t <= 5) stageB(t + 2, 1);
        __builtin_amdgcn_s_barrier();
        asm volatile("s_waitcnt lgkmcnt(0)" ::: "memory");
        __builtin_amdgcn_sched_barrier(0);
        __builtin_amdgcn_s_setprio(1);
        #pragma unroll
        for (int mf = 4; mf < 8; ++mf) {
            MFMA16(acc[mf][0], af1[mf], bf1[0]);
            MFMA16(acc[mf][1], af1[mf], bf1[1]);
            MFMA16(acc[mf][2], af1[mf], bf1[2]);
            MFMA16(acc[mf][3], af1[mf], bf1[3]);
        }
        __builtin_amdgcn_s_setprio(0);
        if (t <= 5) {
            asm volatile("s_waitcnt vmcnt(4)" ::: "memory");   // t+1 landed, B(t+2) in flight
        } else if (t == 6) {
            asm volatile("s_waitcnt vmcnt(0)" ::: "memory");   // drain before last tile
        }
        __builtin_amdgcn_sched_barrier(0);
        __builtin_amdgcn_s_barrier();
    }

    // ---- epilogue: C row = (lane>>4)*4 + r, col = lane&15 (logical rows) ----
    #pragma unroll
    for (int mf = 0; mf < 8; ++mf) {
        #pragma unroll
        for (int nf = 0; nf < 4; ++nf) {
            #pragma unroll
            for (int r = 0; r < 4; ++r) {
                long grow = row0 + wm * 128 + mf * 16 + (lane >> 4) * 4 + r;
                int  gcol = col0 + wn * 64 + nf * 16 + fr;
                float v = acc[mf][nf][r];
                if constexpr (OUT_BF16) ((u16*)Dp)[grow * NCOL + gcol] = f2bf(v);
                else                    ((float*)Dp)[grow * NCOL + gcol] = v;
            }
        }
    }
}

// ---------------------------------------------------------------------------
// Banded temporal attention, LDS-staged via global_load_lds, 1 wave/block,
// NO barriers (wave-private LDS visibility via vmcnt(0)).
// K/V staged with granule-XOR swizzle: physical LDS slot p of row u holds
// LOGICAL chunk p ^ (u&7), achieved by pre-swizzling the GLOBAL source addr
// (LDS dest linear, rule #21). Reading logical chunk c -> slot c ^ (u&7):
// the wave's 64 lanes (64 different u) spread over all 8 bank-quads.
// qkv rows (b,s,t)-ordered; output rows stored PRE-SWIZZLED for gemm3.
// ---------------------------------------------------------------------------
__global__ __launch_bounds__(64) void attn_k(const u16* __restrict__ qkv,
                                             u16* __restrict__ attn) {
    __shared__ u16 Kl[64 * 64];   // [u][slot] 128B rows, swizzled granules
    __shared__ u16 Vl[64 * 64];

    const int tid = threadIdx.x;
    const int bid = blockIdx.x;
    const int h = bid & (H_ - 1);
    const int s = (bid >> 3) & (S_ - 1);
    const int b = bid >> 13;

    const size_t base = ((size_t)((b << 10) | s) * 64) * 1536 + h * 64;

    // ---- stage K,V: 8 issues each; lane l covers (row it*8+(l>>3), slot l&7)
    {
        const int ur = tid >> 3;     // row-within-group
        const int cp = tid & 7;      // physical granule slot in LDS
        #pragma unroll
        for (int it = 0; it < 8; ++it) {
            int u = it * 8 + ur;
            int c = cp ^ (u & 7);    // logical chunk fetched into slot cp
            gload16(qkv + base + (size_t)u * 1536 + 512 + c * 8,
                    (void*)&Kl[it * 512]);
        }
        #pragma unroll
        for (int it = 0; it < 8; ++it) {
            int u = it * 8 + ur;
            int c = cp ^ (u & 7);
            gload16(qkv + base + (size_t)u * 1536 + 1024 + c * 8,
                    (void*)&Vl[it * 512]);
        }
    }

    // ---- Q row (direct, fp32 in regs) — overlaps with staging in flight ----
    float qf[64];
    const int t = tid;
    {
        const u16* qp = qkv + base + (size_t)t * 1536;
        #pragma unroll
        for (int c = 0; c < 8; ++c) {
            u16x8 v = *(const u16x8*)(qp + c * 8);
            #pragma unroll
            for (int j = 0; j < 8; ++j) qf[c * 8 + j] = bf2f(v[j]);
        }
    }
    asm volatile("s_waitcnt vmcnt(0)" ::: "memory");   // staging landed (1 wave)
    __builtin_amdgcn_sched_barrier(0);

    // ---- band scores + softmax ----
    float p[11];
    float m = -1e30f;
    #pragma unroll
    for (int i = 0; i < 11; ++i) {
        int u = t - WIN_ + i;
        if (u >= 0 && u < 64) {
            const int ubase = u * 64;
            const int key = u & 7;
            float dot = 0.f;
            #pragma unroll
            for (int c = 0; c < 8; ++c) {
                // slot c^key holds logical chunk c -> pair with qf[c*8+..]
                u16x8 kv = *(const u16x8*)&Kl[ubase + ((c ^ key) << 3)];
                #pragma unroll
                for (int j = 0; j < 8; ++j) dot += qf[c * 8 + j] * bf2f(kv[j]);
            }
            p[i] = dot * 0.125f;   // hd^-0.5
            m = fmaxf(m, p[i]);
        } else {
            p[i] = -1e30f;
        }
    }
    float sum = 0.f;
    #pragma unroll
    for (int i = 0; i < 11; ++i) {
        int u = t - WIN_ + i;
        float e = (u >= 0 && u < 64) ? __expf(p[i] - m) : 0.f;
        p[i] = e;
        sum += e;
    }
    const float inv = 1.f / sum;

    // ---- PV ----
    float o[64];
    #pragma unroll
    for (int d = 0; d < 64; ++d) o[d] = 0.f;
    #pragma unroll
    for (int i = 0; i < 11; ++i) {
        int u = t - WIN_ + i;
        if (u >= 0 && u < 64) {
            const int ubase = u * 64;
            const int key = u & 7;
            float pv = p[i] * inv;
            #pragma unroll
            for (int c = 0; c < 8; ++c) {
                // slot c^key holds logical chunk c -> accumulate into o[c*8+..]
                u16x8 vv = *(const u16x8*)&Vl[ubase + ((c ^ key) << 3)];
                #pragma unroll
                for (int j = 0; j < 8; ++j) o[c * 8 + j] += pv * bf2f(vv[j]);
            }
        }
    }
    // ---- pre-swizzled store at physical row rid; keys from s ----
    size_t rowbase = ((size_t)((b << 10) | s) * 64 + t) * (size_t)C_;
    const int cb  = (s >> 3) & 1;
    const int key = (s >> 1) & 3;
    #pragma unroll
    for (int c = 0; c < 8; ++c) {
        u16x8 w;
        #pragma unroll
        for (int j = 0; j < 8; ++j) w[j] = f2bf(o[c * 8 + j]);
        int off = (((2 * h + (c >> 2)) ^ cb) << 5) + (((c & 3) ^ key) << 3);
        *(u16x8*)&attn[rowbase + off] = w;
    }
}

// ---------------------------------------------------------------------------
extern "C" void kernel_launch(void* const* d_in, const int* in_sizes, int n_in,
                              void* d_out, int out_size, void* d_ws, size_t ws_size,
                              hipStream_t stream) {
    const float* x    = (const float*)d_in[0];   // (B, N, C) fp32
    const float* Wqkv = (const float*)d_in[1];   // (512, 1536) fp32
    const float* Wout = (const float*)d_in[2];   // (512, 512) fp32
    float* out = (float*)d_out;

    const size_t xc_elems  = (size_t)M_ * C_;      // 67.1M (x_bf16 / attn alias)
    const size_t qkv_elems = (size_t)M_ * 1536;    // 201.3M
    if (ws_size < (xc_elems + qkv_elems) * sizeof(u16)) return;  // 537 MiB

    u16* xb       = (u16*)d_ws;              // [0, 134MB): x_bf16 (b,s,t)-rows
    u16* qkv      = xb + xc_elems;           // [134MB, 537MB), (b,s,t)-rows
    u16* attn_buf = xb;                      // alias: written after xb is dead
    u16* WqkvT    = (u16*)d_out;             // scratch in d_out (dead until gemm3)
    u16* WoutT    = qkv;                     // alias: written after qkv is dead

    // 1) weight + activation prep (bf16, pre-swizzled; x rows permuted)
    prep_w<<<(1536 * 64) / 256, 256, 0, stream>>>(Wqkv, WqkvT, 1536);
    prep_x<<<8192, 256, 0, stream>>>(x, xb);

    // 2) qkv = x @ W_qkv  (256^2 8-phase, bf16 out, rows already permuted)
    gemm8_k<1536, true, false><<<3072, 512, 0, stream>>>(xb, WqkvT, (void*)qkv, 6);

    // 3) banded temporal attention (LDS-staged, swizzled, barrier-free)
    attn_k<<<B_ * H_ * S_, 64, 0, stream>>>(qkv, attn_buf);

    // 4) WoutT into the now-dead qkv region
    prep_w<<<(512 * 64) / 256, 256, 0, stream>>>(Wout, WoutT, 512);

    // 5) out = attn @ W_out  (256^2 8-phase, fp32 out coalesced; A un-permuted
    //    via per-lane gload addresses, attn_buf is L3-resident)
    gemm8_k<512, false, true><<<1024, 512, 0, stream>>>(attn_buf, WoutT, (void*)out, 2);
}